// Round 1
// baseline (5717.490 us; speedup 1.0000x reference)
//
#include <hip/hip_runtime.h>

// Problem constants (from reference)
constexpr int B_ = 16, T_ = 128, S_ = 128;
constexpr int ROWS = B_ * S_;        // 2048
constexpr int NSTEPS = T_ - 1;       // 127
constexpr int TPRED = 20;
constexpr int TOUT = NSTEPS - TPRED; // 107
constexpr int RPB = 8;               // rows per block (8 | 128, blocks never straddle a batch)
constexpr int TB = 256;              // threads per block

// ws layout (floats):
// hn[2][2048][64] hs[2][2048][64] hd[2][2048][128] cn[2048][64] cs[2048][64] cd[2048][128] outs[127][2048][2]
constexpr int OFF_HN = 0;
constexpr int OFF_HS = OFF_HN + 2 * ROWS * 64;
constexpr int OFF_HD = OFF_HS + 2 * ROWS * 64;
constexpr int OFF_CN = OFF_HD + 2 * ROWS * 128;
constexpr int OFF_CS = OFF_CN + ROWS * 64;
constexpr int OFF_CD = OFF_CS + ROWS * 64;
constexpr int OFF_OUTS = OFF_CD + ROWS * 128;
constexpr int STATE_FLOATS = OFF_OUTS; // region to zero each call

__device__ __forceinline__ float sigm(float x) { return 1.f / (1.f + __expf(-x)); }
__device__ __forceinline__ float tanh_(float x) { return 2.f / (1.f + __expf(-2.f * x)) - 1.f; }

__global__ __launch_bounds__(TB) void step_kernel(
    int t,
    const float* __restrict__ input,
    const float* __restrict__ nWx, const float* __restrict__ nWh,
    const float* __restrict__ nWa, const float* __restrict__ nWb, const float* __restrict__ nb,
    const float* __restrict__ sWx, const float* __restrict__ sWh,
    const float* __restrict__ sWa, const float* __restrict__ sWb, const float* __restrict__ sb,
    const float* __restrict__ dWx, const float* __restrict__ dWh,
    const float* __restrict__ dWa, const float* __restrict__ dWb, const float* __restrict__ db,
    const float* __restrict__ onW, const float* __restrict__ onb,
    const float* __restrict__ osW, const float* __restrict__ osb,
    float* __restrict__ ws)
{
    float* hnBuf = ws + OFF_HN;
    float* hsBuf = ws + OFF_HS;
    float* hdBuf = ws + OFF_HD;
    float* cn = ws + OFF_CN;
    float* cs = ws + OFF_CS;
    float* cd = ws + OFF_CD;
    float* outs = ws + OFF_OUTS;

    const int cur = t & 1, nxt = cur ^ 1;
    const float* hnC = hnBuf + cur * ROWS * 64;
    const float* hsC = hsBuf + cur * ROWS * 64;
    const float* hdC = hdBuf + cur * ROWS * 128;
    float* hnN = hnBuf + nxt * ROWS * 64;
    float* hsN = hsBuf + nxt * ROWS * 64;
    float* hdN = hdBuf + nxt * ROWS * 128;

    const int tid = threadIdx.x;
    const int r0 = blockIdx.x * RPB;
    const int b = r0 >> 7;
    const int s0 = r0 & (S_ - 1);

    __shared__ float sh_hn[RPB + 2][64];   // [0] = row r0-1 (halo), [1..RPB] own, [RPB+1] = r0+RPB
    __shared__ float sh_hs[RPB + 2][64];
    __shared__ float sh_hd[RPB + 2][128];
    __shared__ float sh_x[RPB][4];
    __shared__ float sh_gn[RPB][256];
    __shared__ float sh_gs[RPB][256];
    __shared__ float sh_gd[RPB][512];
    __shared__ float sh_hnew[RPB][128];    // dec_in: [0:64)=hn_new, [64:128)=hs_new
    __shared__ float sh_hdnew[RPB][128];

    const bool leftOK = (s0 != 0);
    const bool rightOK = (s0 + RPB != S_);

    // ---- stage old h states (+halo) and x into LDS ----
    for (int i = tid; i < (RPB + 2) * 64; i += TB) {
        int rr = i >> 6, k = i & 63;
        int row = r0 + rr - 1;
        bool v = (rr == 0) ? leftOK : ((rr == RPB + 1) ? rightOK : true);
        sh_hn[rr][k] = v ? hnC[row * 64 + k] : 0.f;
        sh_hs[rr][k] = v ? hsC[row * 64 + k] : 0.f;
    }
    for (int i = tid; i < (RPB + 2) * 128; i += TB) {
        int rr = i >> 7, k = i & 127;
        int row = r0 + rr - 1;
        bool v = (rr == 0) ? leftOK : ((rr == RPB + 1) ? rightOK : true);
        sh_hd[rr][k] = v ? hdC[row * 128 + k] : 0.f;
    }
    if (tid < RPB * 4) {
        int rr = tid >> 2, c = tid & 3;
        sh_x[rr][c] = input[(((b * T_) + t) * S_ + (s0 + rr)) * 4 + c];
    }
    __syncthreads();

    // ---- phase A: n-cell and s-cell gate GEMMs (thread j owns column j of both) ----
    {
        const int j = tid;
        float accn[RPB], accs[RPB];
#pragma unroll
        for (int r = 0; r < RPB; ++r) {
            accn[r] = nb[j] + sh_x[r][0] * nWx[j] + sh_x[r][1] * nWx[256 + j] + sh_x[r][2] * nWx[512 + j];
            accs[r] = sb[j] + sh_x[r][3] * sWx[j];
        }
        for (int k = 0; k < 64; ++k) {
            float wh = nWh[k * 256 + j], wa = nWa[k * 256 + j], wb = nWb[k * 256 + j];
            float vh = sWh[k * 256 + j], va = sWa[k * 256 + j], vb = sWb[k * 256 + j];
#pragma unroll
            for (int r = 0; r < RPB; ++r) {
                // h_a[r] = h[s+1] -> sh[r+2]; h_b[r] = h[s-1] -> sh[r]
                accn[r] += sh_hn[r + 1][k] * wh + sh_hn[r + 2][k] * wa + sh_hn[r][k] * wb;
                accs[r] += sh_hs[r + 1][k] * vh + sh_hs[r + 2][k] * va + sh_hs[r][k] * vb;
            }
        }
#pragma unroll
        for (int r = 0; r < RPB; ++r) { sh_gn[r][j] = accn[r]; sh_gs[r][j] = accs[r]; }
    }
    __syncthreads();

    // ---- epilogue A: gate combine for n and s cells ----
#pragma unroll
    for (int p = 0; p < 2; ++p) {
        int item = tid + p * TB;          // 512 items = 8 rows x 64
        int r = item >> 6, k = item & 63;
        int row = r0 + r;
        {
            float gi = sh_gn[r][k], gf = sh_gn[r][64 + k], gu = sh_gn[r][128 + k], go = sh_gn[r][192 + k];
            float c2 = sigm(gf) * cn[row * 64 + k] + sigm(gi) * tanh_(gu);
            float h2 = sigm(go) * tanh_(c2);
            cn[row * 64 + k] = c2; hnN[row * 64 + k] = h2; sh_hnew[r][k] = h2;
        }
        {
            float gi = sh_gs[r][k], gf = sh_gs[r][64 + k], gu = sh_gs[r][128 + k], go = sh_gs[r][192 + k];
            float c2 = sigm(gf) * cs[row * 64 + k] + sigm(gi) * tanh_(gu);
            float h2 = sigm(go) * tanh_(c2);
            cs[row * 64 + k] = c2; hsN[row * 64 + k] = h2; sh_hnew[r][64 + k] = h2;
        }
    }
    __syncthreads();

    // ---- phase B: d-cell gate GEMM (thread j owns columns j and j+256) ----
    {
        const int j = tid;
        float a0[RPB], a1[RPB];
#pragma unroll
        for (int r = 0; r < RPB; ++r) { a0[r] = db[j]; a1[r] = db[256 + j]; }
        for (int k = 0; k < 128; ++k) { // dec_in @ dWx
            float w0 = dWx[k * 512 + j], w1 = dWx[k * 512 + 256 + j];
#pragma unroll
            for (int r = 0; r < RPB; ++r) { float a = sh_hnew[r][k]; a0[r] += a * w0; a1[r] += a * w1; }
        }
        for (int k = 0; k < 128; ++k) { // hd @ dWh
            float w0 = dWh[k * 512 + j], w1 = dWh[k * 512 + 256 + j];
#pragma unroll
            for (int r = 0; r < RPB; ++r) { float a = sh_hd[r + 1][k]; a0[r] += a * w0; a1[r] += a * w1; }
        }
        for (int k = 0; k < 128; ++k) { // hd_a (s+1) @ dWa
            float w0 = dWa[k * 512 + j], w1 = dWa[k * 512 + 256 + j];
#pragma unroll
            for (int r = 0; r < RPB; ++r) { float a = sh_hd[r + 2][k]; a0[r] += a * w0; a1[r] += a * w1; }
        }
        for (int k = 0; k < 128; ++k) { // hd_b (s-1) @ dWb
            float w0 = dWb[k * 512 + j], w1 = dWb[k * 512 + 256 + j];
#pragma unroll
            for (int r = 0; r < RPB; ++r) { float a = sh_hd[r][k]; a0[r] += a * w0; a1[r] += a * w1; }
        }
#pragma unroll
        for (int r = 0; r < RPB; ++r) { sh_gd[r][j] = a0[r]; sh_gd[r][256 + j] = a1[r]; }
    }
    __syncthreads();

    // ---- epilogue B: d-cell gate combine ----
#pragma unroll
    for (int p = 0; p < 4; ++p) {
        int item = tid + p * TB;          // 1024 items = 8 rows x 128
        int r = item >> 7, k = item & 127;
        int row = r0 + r;
        float gi = sh_gd[r][k], gf = sh_gd[r][128 + k], gu = sh_gd[r][256 + k], go = sh_gd[r][384 + k];
        float c2 = sigm(gf) * cd[row * 128 + k] + sigm(gi) * tanh_(gu);
        float h2 = sigm(go) * tanh_(c2);
        cd[row * 128 + k] = c2; hdN[row * 128 + k] = h2; sh_hdnew[r][k] = h2;
    }
    __syncthreads();

    // ---- output heads: 16 groups of 16 lanes; group p -> (row r, head) ----
    {
        int p = tid >> 4, l = tid & 15;   // p in [0,16)
        int r = p >> 1, head = p & 1;
        const float* W = head ? osW : onW;
        float partial = 0.f;
        for (int k = l; k < 128; k += 16) partial += sh_hdnew[r][k] * W[k];
        for (int off = 8; off; off >>= 1) partial += __shfl_down(partial, off, 16);
        if (l == 0) outs[(t * ROWS + (r0 + r)) * 2 + head] = partial + (head ? osb[0] : onb[0]);
    }
}

// Assemble data outputs for t in [20,126] from stored head outputs (avoids any
// same-step cross-block dependency on out0(s-1)).
__global__ __launch_bounds__(TB) void assemble_kernel(
    const float* __restrict__ input, const float* __restrict__ ws, float* __restrict__ out)
{
    const float* outs = ws + OFF_OUTS;
    int idx = blockIdx.x * TB + threadIdx.x;  // (b, tt, s)
    if (idx >= B_ * TOUT * S_) return;
    int s = idx & 127;
    int tmp = idx >> 7;
    int tt = tmp % TOUT;
    int b = tmp / TOUT;
    int t = tt + TPRED;
    int row = b * S_ + s;
    float o0 = outs[(t * ROWS + row) * 2 + 0];
    float o1 = outs[(t * ROWS + row) * 2 + 1];
    float inflow = (s == 0) ? input[(((b * T_) + (t + 1)) * S_ + 0) * 4 + 1]
                            : outs[(t * ROWS + row - 1) * 2 + 0];
    float numc = input[(((b * T_) + t) * S_ + s) * 4 + 2] + inflow - o0;
    float spd = (s == 0) ? input[(((b * T_) + (t + 1)) * S_ + 0) * 4 + 3] : o1;
    float4 v = make_float4(o0, inflow, numc, spd);
    reinterpret_cast<float4*>(out)[idx] = v;
}

extern "C" void kernel_launch(void* const* d_in, const int* in_sizes, int n_in,
                              void* d_out, int out_size, void* d_ws, size_t ws_size,
                              hipStream_t stream) {
    const float* input = (const float*)d_in[0];
    const float* nWx = (const float*)d_in[1];
    const float* nWh = (const float*)d_in[2];
    const float* nWa = (const float*)d_in[3];
    const float* nWb = (const float*)d_in[4];
    const float* nb  = (const float*)d_in[5];
    const float* sWx = (const float*)d_in[6];
    const float* sWh = (const float*)d_in[7];
    const float* sWa = (const float*)d_in[8];
    const float* sWb = (const float*)d_in[9];
    const float* sb  = (const float*)d_in[10];
    const float* dWx = (const float*)d_in[11];
    const float* dWh = (const float*)d_in[12];
    const float* dWa = (const float*)d_in[13];
    const float* dWb = (const float*)d_in[14];
    const float* db  = (const float*)d_in[15];
    const float* onW = (const float*)d_in[16];
    const float* onb = (const float*)d_in[17];
    const float* osW = (const float*)d_in[18];
    const float* osb = (const float*)d_in[19];

    float* ws = (float*)d_ws;

    // zero the recurrent state region (ws is poisoned 0xAA before every call)
    hipMemsetAsync(ws, 0, (size_t)STATE_FLOATS * sizeof(float), stream);

    for (int t = 0; t < NSTEPS; ++t) {
        step_kernel<<<dim3(ROWS / RPB), dim3(TB), 0, stream>>>(
            t, input,
            nWx, nWh, nWa, nWb, nb,
            sWx, sWh, sWa, sWb, sb,
            dWx, dWh, dWa, dWb, db,
            onW, onb, osW, osb, ws);
    }

    int nout = B_ * TOUT * S_;
    assemble_kernel<<<dim3((nout + TB - 1) / TB), dim3(TB), 0, stream>>>(input, ws, (float*)d_out);
}

// Round 2
// 4714.883 us; speedup vs baseline: 1.2126x; 1.2126x over previous
//
#include <hip/hip_runtime.h>

// Problem constants (from reference)
constexpr int B_ = 16, T_ = 128, S_ = 128;
constexpr int ROWS = B_ * S_;        // 2048
constexpr int NSTEPS = T_ - 1;       // 127
constexpr int TPRED = 20;
constexpr int TOUT = NSTEPS - TPRED; // 107
constexpr int RPB = 8;               // rows per block (blocks never straddle a batch)
constexpr int TB = 1024;             // threads per block -> 16 waves/CU at grid=256

// ws layout (floats)
constexpr int OFF_HN = 0;
constexpr int OFF_HS = OFF_HN + 2 * ROWS * 64;
constexpr int OFF_HD = OFF_HS + 2 * ROWS * 64;
constexpr int OFF_CN = OFF_HD + 2 * ROWS * 128;
constexpr int OFF_CS = OFF_CN + ROWS * 64;
constexpr int OFF_CD = OFF_CS + ROWS * 64;
constexpr int OFF_OUTS = OFF_CD + ROWS * 128;
constexpr int STATE_FLOATS = OFF_OUTS;

__device__ __forceinline__ float sigm(float x) { return 1.f / (1.f + __expf(-x)); }
__device__ __forceinline__ float tanh_(float x) { return 2.f / (1.f + __expf(-2.f * x)) - 1.f; }

__global__ __launch_bounds__(TB) void step_kernel(
    int t,
    const float* __restrict__ input,
    const float* __restrict__ nWx, const float* __restrict__ nWh,
    const float* __restrict__ nWa, const float* __restrict__ nWb, const float* __restrict__ nb,
    const float* __restrict__ sWx, const float* __restrict__ sWh,
    const float* __restrict__ sWa, const float* __restrict__ sWb, const float* __restrict__ sb,
    const float* __restrict__ dWx, const float* __restrict__ dWh,
    const float* __restrict__ dWa, const float* __restrict__ dWb, const float* __restrict__ db,
    const float* __restrict__ onW, const float* __restrict__ onb,
    const float* __restrict__ osW, const float* __restrict__ osb,
    float* __restrict__ ws)
{
    float* hnBuf = ws + OFF_HN;
    float* hsBuf = ws + OFF_HS;
    float* hdBuf = ws + OFF_HD;
    float* cn = ws + OFF_CN;
    float* cs = ws + OFF_CS;
    float* cd = ws + OFF_CD;
    float* outs = ws + OFF_OUTS;

    const int cur = t & 1, nxt = cur ^ 1;
    const float* hnC = hnBuf + cur * ROWS * 64;
    const float* hsC = hsBuf + cur * ROWS * 64;
    const float* hdC = hdBuf + cur * ROWS * 128;
    float* hnN = hnBuf + nxt * ROWS * 64;
    float* hsN = hsBuf + nxt * ROWS * 64;
    float* hdN = hdBuf + nxt * ROWS * 128;

    const int tid = threadIdx.x;
    const int r0 = blockIdx.x * RPB;
    const int b = r0 >> 7;
    const int s0 = r0 & (S_ - 1);

    __shared__ float sh_hn[RPB + 2][64];   // [0]=row r0-1 halo, [1..RPB] own, [RPB+1]=row r0+RPB
    __shared__ float sh_hs[RPB + 2][64];
    __shared__ float sh_hd[RPB + 2][128];
    __shared__ float sh_x[RPB][4];
    __shared__ float sh_hnew[RPB][128];    // dec_in: [0:64)=hn_new, [64:128)=hs_new
    __shared__ float sh_hdnew[RPB][128];
    // 32KB union: phase A partials (gn[2][8][256] 16KB + gs[2][8][256] 16KB)
    //             phase B partials (gd[2][8][512] 32KB) -- barrier-separated reuse
    __shared__ float sh_u[8192];
#define GN_P(kh, r, j) sh_u[(kh) * 2048 + (r) * 256 + (j)]
#define GS_P(kh, r, j) sh_u[4096 + (kh) * 2048 + (r) * 256 + (j)]
#define GD_P(kh, r, j) sh_u[(kh) * 4096 + (r) * 512 + (j)]

    const bool leftOK = (s0 != 0);
    const bool rightOK = (s0 + RPB != S_);

    // ---- stage old h states (+halo) and x into LDS ----
    if (tid < (RPB + 2) * 64) {
        int rr = tid >> 6, k = tid & 63;
        int row = r0 + rr - 1;
        bool v = (rr == 0) ? leftOK : ((rr == RPB + 1) ? rightOK : true);
        sh_hn[rr][k] = v ? hnC[row * 64 + k] : 0.f;
        sh_hs[rr][k] = v ? hsC[row * 64 + k] : 0.f;
    }
    for (int i = tid; i < (RPB + 2) * 128; i += TB) {
        int rr = i >> 7, k = i & 127;
        int row = r0 + rr - 1;
        bool v = (rr == 0) ? leftOK : ((rr == RPB + 1) ? rightOK : true);
        sh_hd[rr][k] = v ? hdC[row * 128 + k] : 0.f;
    }
    if (tid < RPB * 4) {
        int rr = tid >> 2, c = tid & 3;
        sh_x[rr][c] = input[(((b * T_) + t) * S_ + (s0 + rr)) * 4 + c];
    }
    __syncthreads();

    // ---- phase A: n/s-cell gate GEMMs. grp 0,1 = n-cell k-halves; 2,3 = s-cell ----
    {
        const int j = tid & 255;
        const int grp = tid >> 8;   // wave-uniform
        float acc[RPB];
        if (grp < 2) {
            const int k0 = grp * 32;
#pragma unroll
            for (int r = 0; r < RPB; ++r)
                acc[r] = (grp == 0)
                    ? nb[j] + sh_x[r][0] * nWx[j] + sh_x[r][1] * nWx[256 + j] + sh_x[r][2] * nWx[512 + j]
                    : 0.f;
#pragma unroll 4
            for (int k = k0; k < k0 + 32; ++k) {
                float wh = nWh[k * 256 + j], wa = nWa[k * 256 + j], wb = nWb[k * 256 + j];
#pragma unroll
                for (int r = 0; r < RPB; ++r)
                    acc[r] += sh_hn[r + 1][k] * wh + sh_hn[r + 2][k] * wa + sh_hn[r][k] * wb;
            }
#pragma unroll
            for (int r = 0; r < RPB; ++r) GN_P(grp, r, j) = acc[r];
        } else {
            const int kh = grp - 2;
            const int k0 = kh * 32;
#pragma unroll
            for (int r = 0; r < RPB; ++r)
                acc[r] = (kh == 0) ? sb[j] + sh_x[r][3] * sWx[j] : 0.f;
#pragma unroll 4
            for (int k = k0; k < k0 + 32; ++k) {
                float vh = sWh[k * 256 + j], va = sWa[k * 256 + j], vb = sWb[k * 256 + j];
#pragma unroll
                for (int r = 0; r < RPB; ++r)
                    acc[r] += sh_hs[r + 1][k] * vh + sh_hs[r + 2][k] * va + sh_hs[r][k] * vb;
            }
#pragma unroll
            for (int r = 0; r < RPB; ++r) GS_P(kh, r, j) = acc[r];
        }
    }
    __syncthreads();

    // ---- epilogue A: gate combine, n-cell (tid<512) and s-cell (tid>=512) ----
    if (tid < 512) {
        int r = tid >> 6, k = tid & 63;
        int row = r0 + r;
        float gi = GN_P(0, r, k)       + GN_P(1, r, k);
        float gf = GN_P(0, r, 64 + k)  + GN_P(1, r, 64 + k);
        float gu = GN_P(0, r, 128 + k) + GN_P(1, r, 128 + k);
        float go = GN_P(0, r, 192 + k) + GN_P(1, r, 192 + k);
        float c2 = sigm(gf) * cn[row * 64 + k] + sigm(gi) * tanh_(gu);
        float h2 = sigm(go) * tanh_(c2);
        cn[row * 64 + k] = c2; hnN[row * 64 + k] = h2; sh_hnew[r][k] = h2;
    } else {
        int t2 = tid - 512;
        int r = t2 >> 6, k = t2 & 63;
        int row = r0 + r;
        float gi = GS_P(0, r, k)       + GS_P(1, r, k);
        float gf = GS_P(0, r, 64 + k)  + GS_P(1, r, 64 + k);
        float gu = GS_P(0, r, 128 + k) + GS_P(1, r, 128 + k);
        float go = GS_P(0, r, 192 + k) + GS_P(1, r, 192 + k);
        float c2 = sigm(gf) * cs[row * 64 + k] + sigm(gi) * tanh_(gu);
        float h2 = sigm(go) * tanh_(c2);
        cs[row * 64 + k] = c2; hsN[row * 64 + k] = h2; sh_hnew[r][64 + k] = h2;
    }
    __syncthreads();

    // ---- phase B: d-cell gate GEMM. kh=0: Wx+Wh halves; kh=1: Wa+Wb halves ----
    {
        const int j = tid & 511;
        const int kh = tid >> 9;    // wave-uniform
        float acc[RPB];
        if (kh == 0) {
#pragma unroll
            for (int r = 0; r < RPB; ++r) acc[r] = db[j];
#pragma unroll 4
            for (int k = 0; k < 128; ++k) {   // dec_in @ dWx
                float w = dWx[k * 512 + j];
#pragma unroll
                for (int r = 0; r < RPB; ++r) acc[r] += sh_hnew[r][k] * w;
            }
#pragma unroll 4
            for (int k = 0; k < 128; ++k) {   // hd @ dWh
                float w = dWh[k * 512 + j];
#pragma unroll
                for (int r = 0; r < RPB; ++r) acc[r] += sh_hd[r + 1][k] * w;
            }
        } else {
#pragma unroll
            for (int r = 0; r < RPB; ++r) acc[r] = 0.f;
#pragma unroll 4
            for (int k = 0; k < 128; ++k) {   // hd_a (s+1) @ dWa
                float w = dWa[k * 512 + j];
#pragma unroll
                for (int r = 0; r < RPB; ++r) acc[r] += sh_hd[r + 2][k] * w;
            }
#pragma unroll 4
            for (int k = 0; k < 128; ++k) {   // hd_b (s-1) @ dWb
                float w = dWb[k * 512 + j];
#pragma unroll
                for (int r = 0; r < RPB; ++r) acc[r] += sh_hd[r][k] * w;
            }
        }
#pragma unroll
        for (int r = 0; r < RPB; ++r) GD_P(kh, r, j) = acc[r];
    }
    __syncthreads();

    // ---- epilogue B: d-cell gate combine (1024 items = 8 rows x 128) ----
    {
        int r = tid >> 7, k = tid & 127;
        int row = r0 + r;
        float gi = GD_P(0, r, k)       + GD_P(1, r, k);
        float gf = GD_P(0, r, 128 + k) + GD_P(1, r, 128 + k);
        float gu = GD_P(0, r, 256 + k) + GD_P(1, r, 256 + k);
        float go = GD_P(0, r, 384 + k) + GD_P(1, r, 384 + k);
        float c2 = sigm(gf) * cd[row * 128 + k] + sigm(gi) * tanh_(gu);
        float h2 = sigm(go) * tanh_(c2);
        cd[row * 128 + k] = c2; hdN[row * 128 + k] = h2; sh_hdnew[r][k] = h2;
    }
    __syncthreads();

    // ---- output heads: one wave per (row, head) ----
    {
        int p = tid >> 6, l = tid & 63;    // p in [0,16)
        int r = p >> 1, head = p & 1;
        const float* W = head ? osW : onW;
        float partial = sh_hdnew[r][l] * W[l] + sh_hdnew[r][64 + l] * W[64 + l];
#pragma unroll
        for (int off = 32; off; off >>= 1) partial += __shfl_down(partial, off);
        if (l == 0) outs[(t * ROWS + (r0 + r)) * 2 + head] = partial + (head ? osb[0] : onb[0]);
    }
#undef GN_P
#undef GS_P
#undef GD_P
}

// Assemble data outputs for t in [20,126] from stored head outputs.
__global__ __launch_bounds__(256) void assemble_kernel(
    const float* __restrict__ input, const float* __restrict__ ws, float* __restrict__ out)
{
    const float* outs = ws + OFF_OUTS;
    int idx = blockIdx.x * 256 + threadIdx.x;  // (b, tt, s)
    if (idx >= B_ * TOUT * S_) return;
    int s = idx & 127;
    int tmp = idx >> 7;
    int tt = tmp % TOUT;
    int b = tmp / TOUT;
    int t = tt + TPRED;
    int row = b * S_ + s;
    float o0 = outs[(t * ROWS + row) * 2 + 0];
    float o1 = outs[(t * ROWS + row) * 2 + 1];
    float inflow = (s == 0) ? input[(((b * T_) + (t + 1)) * S_ + 0) * 4 + 1]
                            : outs[(t * ROWS + row - 1) * 2 + 0];
    float numc = input[(((b * T_) + t) * S_ + s) * 4 + 2] + inflow - o0;
    float spd = (s == 0) ? input[(((b * T_) + (t + 1)) * S_ + 0) * 4 + 3] : o1;
    float4 v = make_float4(o0, inflow, numc, spd);
    reinterpret_cast<float4*>(out)[idx] = v;
}

extern "C" void kernel_launch(void* const* d_in, const int* in_sizes, int n_in,
                              void* d_out, int out_size, void* d_ws, size_t ws_size,
                              hipStream_t stream) {
    const float* input = (const float*)d_in[0];
    const float* nWx = (const float*)d_in[1];
    const float* nWh = (const float*)d_in[2];
    const float* nWa = (const float*)d_in[3];
    const float* nWb = (const float*)d_in[4];
    const float* nb  = (const float*)d_in[5];
    const float* sWx = (const float*)d_in[6];
    const float* sWh = (const float*)d_in[7];
    const float* sWa = (const float*)d_in[8];
    const float* sWb = (const float*)d_in[9];
    const float* sb  = (const float*)d_in[10];
    const float* dWx = (const float*)d_in[11];
    const float* dWh = (const float*)d_in[12];
    const float* dWa = (const float*)d_in[13];
    const float* dWb = (const float*)d_in[14];
    const float* db  = (const float*)d_in[15];
    const float* onW = (const float*)d_in[16];
    const float* onb = (const float*)d_in[17];
    const float* osW = (const float*)d_in[18];
    const float* osb = (const float*)d_in[19];

    float* ws = (float*)d_ws;

    // zero the recurrent state region (ws is poisoned 0xAA before every call)
    hipMemsetAsync(ws, 0, (size_t)STATE_FLOATS * sizeof(float), stream);

    for (int t = 0; t < NSTEPS; ++t) {
        step_kernel<<<dim3(ROWS / RPB), dim3(TB), 0, stream>>>(
            t, input,
            nWx, nWh, nWa, nWb, nb,
            sWx, sWh, sWa, sWb, sb,
            dWx, dWh, dWa, dWb, db,
            onW, onb, osW, osb, ws);
    }

    int nout = B_ * TOUT * S_;
    assemble_kernel<<<dim3((nout + 255) / 256), dim3(256), 0, stream>>>(input, ws, (float*)d_out);
}